// Round 1
// 262.438 us; speedup vs baseline: 1.0343x; 1.0343x over previous
//
#include <hip/hip_runtime.h>
#include <math.h>

#define N_NODES 50000
#define E_RAW 800000
#define E_TOT 850000
#define NEG_SLOPE 0.2f
#define NBLK ((N_NODES + 1023) / 1024)
#define G1_BLOCKS ((N_NODES + 63) / 64)          // gemm1 MFMA part: BM=64, 256 thr
#define G2_BLOCKS ((E_TOT / 4 + 255) / 256)      // deg_rank part: 256 thr, 4 edges/thr

typedef __attribute__((ext_vector_type(8))) short bf16x8;
typedef __attribute__((ext_vector_type(4))) float f32x4;

__device__ __forceinline__ float lrelu(float a) { return a > 0.f ? a : NEG_SLOPE * a; }

__device__ __forceinline__ unsigned f2bf(float f) {
    unsigned u = __float_as_uint(f);
    return (u + 0x7fff + ((u >> 16) & 1)) >> 16;
}
__device__ __forceinline__ unsigned pack2(float a, float b) {
    return f2bf(a) | (f2bf(b) << 16);
}
__device__ __forceinline__ float bflo(unsigned p) { return __uint_as_float(p << 16); }
__device__ __forceinline__ float bfhi(unsigned p) { return __uint_as_float(p & 0xffff0000u); }

// ---------------- prep: W1 (128x128 fp32 row-major) -> Btg[col][k] bf16 ----------------
__global__ void k_prepB(const float* __restrict__ W, unsigned* __restrict__ Btg) {
    int c = blockIdx.x;            // 0..127 output column of W1
    int tq = threadIdx.x;          // 0..63  word = k/2
    float a = W[(2 * tq) * 128 + c];
    float b = W[(2 * tq + 1) * 128 + c];
    Btg[c * 64 + tq] = pack2(a, b);
}

// ---------------- FUSED: gemm1 MFMA (blocks < G1) || deg_rank (blocks >= G1) ----------------
// gemm1: h1 = x @ W1 via v_mfma_f32_16x16x32_bf16. BM=64, 4 waves, each wave 16 rows x 128 cols.
//   A (x rows) staged fp32->bf16 in LDS, XOR-swizzled (row pitch 256B = 16-way conflict unswizzled).
//   W fragments read from pre-transposed global Btg (32KB, L1/L2-hot).
//   mfma(Wfrag, xfrag, acc): D col=lane&15 -> node row; D row=4*(lane>>4)+j -> feature.
//   => bf16 pack of C needs no shuffles; attn1 epilogue reduces only over lane>>4.
// deg_rank: histogram + rank of dst cols, unchanged.
__global__ void k_gemm1_deg(const float* __restrict__ A, const unsigned* __restrict__ Btg,
                            const float* __restrict__ aux, uint2* __restrict__ C,
                            float* __restrict__ es, float* __restrict__ ed,
                            const int* __restrict__ ei, int* __restrict__ deg,
                            unsigned short* __restrict__ rank) {
    __shared__ unsigned As[64 * 64];   // 16 KB: 64 rows x 128 bf16, swizzled
    if (blockIdx.x >= G1_BLOCKS) {
        // ---- deg_rank body (256 threads) ----
        int t = (blockIdx.x - G1_BLOCKS) * 256 + threadIdx.x;
        int e0 = 4 * t;
        if (e0 >= E_TOT) return;
        int col[4];
        if (e0 + 3 < E_RAW) {
            int4 c4 = ((const int4*)(ei + E_RAW))[t];
            col[0] = c4.x; col[1] = c4.y; col[2] = c4.z; col[3] = c4.w;
        } else {
#pragma unroll
            for (int i = 0; i < 4; ++i) {
                int e = e0 + i;
                col[i] = (e < E_RAW) ? ei[E_RAW + e] : (e - E_RAW);
            }
        }
        unsigned short rk[4];
#pragma unroll
        for (int i = 0; i < 4; ++i)
            rk[i] = (e0 + i < E_TOT) ? (unsigned short)atomicAdd(&deg[col[i]], 1) : (unsigned short)0;
        if (e0 + 3 < E_TOT) {
            ushort4 v; v.x = rk[0]; v.y = rk[1]; v.z = rk[2]; v.w = rk[3];
            ((ushort4*)rank)[t] = v;
        } else {
#pragma unroll
            for (int i = 0; i < 4; ++i)
                if (e0 + i < E_TOT) rank[e0 + i] = rk[i];
        }
        return;
    }
    // ---- gemm1 MFMA body ----
    int t = threadIdx.x;
    int m0 = blockIdx.x * 64;
    int rows = min(64, N_NODES - m0);
    // stage x tile: fp32 -> bf16, swizzle byte ^= (row&7)<<4 (bits 4-6, preserves 8B chunks)
    const float4* A4 = (const float4*)(A + (size_t)m0 * 128);
    for (int i = t; i < rows * 32; i += 256) {
        int row = i >> 5, k4 = i & 31;
        float4 v = A4[i];
        int byte = (k4 * 8) ^ ((row & 7) << 4);
        unsigned* p = &As[row * 64 + (byte >> 2)];
        p[0] = pack2(v.x, v.y);
        p[1] = pack2(v.z, v.w);
    }
    __syncthreads();
    int lane = t & 63, wave = t >> 6;
    int r15 = lane & 15, g = lane >> 4;
    int arow = wave * 16 + r15;           // local node row for this lane's D-column
    f32x4 acc[8];
#pragma unroll
    for (int i = 0; i < 8; ++i) acc[i] = (f32x4){0.f, 0.f, 0.f, 0.f};
    const char* Abase = (const char*)As + arow * 256;
    int swz = (arow & 7) << 4;
    const char* Bbase = (const char*)Btg;
#pragma unroll
    for (int s = 0; s < 4; ++s) {
        // x frag: x[arow][32s + 8g + (0..7)]  (16B LDS read, swizzled)
        bf16x8 xf = *(const bf16x8*)(Abase + ((64 * s + 16 * g) ^ swz));
#pragma unroll
        for (int tt = 0; tt < 8; ++tt) {
            // W frag: W1[32s+8g+(0..7)][16tt + r15]  (16B from hot global Btg)
            bf16x8 wf = *(const bf16x8*)(Bbase + ((16 * tt + r15) * 256 + 64 * s + 16 * g));
            acc[tt] = __builtin_amdgcn_mfma_f32_16x16x32_bf16(wf, xf, acc[tt], 0, 0, 0);
        }
    }
    int grow = m0 + arow;
    bool valid = (arow < rows);
    // C store: lane holds features 16tt+4g+j (j=0..3) for node grow -> uint2 idx 4tt+g
    if (valid) {
        uint2* C2 = C + (size_t)grow * 32;
#pragma unroll
        for (int tt = 0; tt < 8; ++tt) {
            uint2 v; v.x = pack2(acc[tt][0], acc[tt][1]); v.y = pack2(acc[tt][2], acc[tt][3]);
            C2[4 * tt + g] = v;
        }
    }
    // attn1 epilogue: f = 16tt+4g+j, head h = tt>>1, fin = f&31 = 16*(tt&1)+4g+j
    float ps0 = 0.f, ps1 = 0.f, ps2 = 0.f, ps3 = 0.f;
    float pd0 = 0.f, pd1 = 0.f, pd2 = 0.f, pd3 = 0.f;
#pragma unroll
    for (int tt = 0; tt < 8; ++tt) {
        int h = tt >> 1;
        int fin = 16 * (tt & 1) + 4 * g;
        float4 alv = *(const float4*)(aux + h * 64 + fin);
        float4 arv = *(const float4*)(aux + h * 64 + 32 + fin);
        float s4 = acc[tt][0] * alv.x + acc[tt][1] * alv.y + acc[tt][2] * alv.z + acc[tt][3] * alv.w;
        float d4 = acc[tt][0] * arv.x + acc[tt][1] * arv.y + acc[tt][2] * arv.z + acc[tt][3] * arv.w;
        if (h == 0) { ps0 += s4; pd0 += d4; }
        else if (h == 1) { ps1 += s4; pd1 += d4; }
        else if (h == 2) { ps2 += s4; pd2 += d4; }
        else { ps3 += s4; pd3 += d4; }
    }
#pragma unroll
    for (int mask = 16; mask <= 32; mask <<= 1) {
        ps0 += __shfl_xor(ps0, mask); ps1 += __shfl_xor(ps1, mask);
        ps2 += __shfl_xor(ps2, mask); ps3 += __shfl_xor(ps3, mask);
        pd0 += __shfl_xor(pd0, mask); pd1 += __shfl_xor(pd1, mask);
        pd2 += __shfl_xor(pd2, mask); pd3 += __shfl_xor(pd3, mask);
    }
    if (valid) {
        float psg = (g == 0) ? ps0 : (g == 1) ? ps1 : (g == 2) ? ps2 : ps3;
        float pdg = (g == 0) ? pd0 : (g == 1) ? pd1 : (g == 2) ? pd2 : pd3;
        es[grow * 4 + g] = psg;
        ed[grow * 4 + g] = pdg;
    }
}

__global__ void k_scan1(const int* __restrict__ deg, int* __restrict__ off, int* __restrict__ blksum) {
    __shared__ int sh[1024];
    int b = blockIdx.x;
    int i = b * 1024 + threadIdx.x;
    int v = (i < N_NODES) ? deg[i] : 0;
    sh[threadIdx.x] = v;
    __syncthreads();
    for (int ofs = 1; ofs < 1024; ofs <<= 1) {
        int t = (threadIdx.x >= ofs) ? sh[threadIdx.x - ofs] : 0;
        __syncthreads();
        sh[threadIdx.x] += t;
        __syncthreads();
    }
    if (i < N_NODES) off[i] = sh[threadIdx.x] - v;
    if (threadIdx.x == 1023) blksum[b] = sh[1023];
}

__global__ void k_scan2(const int* __restrict__ blksum, int* __restrict__ blkoff, int* __restrict__ off) {
    int l = threadIdx.x & 63;
    int v = (l < NBLK) ? blksum[l] : 0;
    int incl = v;
    for (int ofs = 1; ofs < 64; ofs <<= 1) {
        int t = __shfl_up(incl, ofs);
        if (l >= ofs) incl += t;
    }
    if (l < NBLK) blkoff[l] = incl - v;
    if (l == 63) off[N_NODES] = incl;
}

__global__ void k_scan3(int* __restrict__ off, const int* __restrict__ blkoff) {
    int i = blockIdx.x * blockDim.x + threadIdx.x;
    if (i >= N_NODES) return;
    off[i] += blkoff[i >> 10];
}

// atomic-free scatter: position = off[col] + rank[e]
__global__ void k_scatter2(const int* __restrict__ ei, const int* __restrict__ off,
                           const unsigned short* __restrict__ rank,
                           unsigned short* __restrict__ srcs) {
    int t = blockIdx.x * blockDim.x + threadIdx.x;
    int e0 = 4 * t;
    if (e0 >= E_TOT) return;
    int row[4], col[4], rk[4];
    if (e0 + 3 < E_TOT && e0 + 3 < E_RAW) {
        int4 r4 = ((const int4*)ei)[t];
        int4 c4 = ((const int4*)(ei + E_RAW))[t];
        ushort4 k4 = ((const ushort4*)rank)[t];
        row[0] = r4.x; row[1] = r4.y; row[2] = r4.z; row[3] = r4.w;
        col[0] = c4.x; col[1] = c4.y; col[2] = c4.z; col[3] = c4.w;
        rk[0] = k4.x; rk[1] = k4.y; rk[2] = k4.z; rk[3] = k4.w;
    } else {
#pragma unroll
        for (int i = 0; i < 4; ++i) {
            int e = e0 + i;
            if (e < E_RAW) { row[i] = ei[e]; col[i] = ei[E_RAW + e]; }
            else { row[i] = e - E_RAW; col[i] = row[i]; }
            rk[i] = (e < E_TOT) ? rank[e] : 0;
        }
    }
#pragma unroll
    for (int i = 0; i < 4; ++i)
        if (e0 + i < E_TOT) srcs[off[col[i]] + rk[i]] = (unsigned short)row[i];
}

// ---------------- GEMM 2/3: NC=64 (unchanged this round) ----------------
template<int K, int EPI>
__global__ void k_gemm23(const float* __restrict__ A, const float* __restrict__ B,
                         const float* __restrict__ aux, void* __restrict__ Cv,
                         float* __restrict__ es, float* __restrict__ ed) {
    constexpr int MT = 32;
    __shared__ float As[MT * K];
    int m0 = blockIdx.x * MT;
    int t = threadIdx.x, g = t >> 4, l = t & 15;
    int rows = min(MT, N_NODES - m0);
    const float4* A4 = (const float4*)(A + (size_t)m0 * K);
    float4* S4 = (float4*)As;
    for (int i = t; i < rows * (K / 4); i += 64) S4[i] = A4[i];
    __syncthreads();
    float acc[8][4];
#pragma unroll
    for (int r = 0; r < 8; ++r)
#pragma unroll
        for (int c = 0; c < 4; ++c) acc[r][c] = 0.f;
    const float4* B4 = (const float4*)B;   // row k = 16 float4
    for (int kk = 0; kk < K / 4; ++kk) {
        float4 b0 = B4[(4 * kk + 0) * 16 + l];
        float4 b1 = B4[(4 * kk + 1) * 16 + l];
        float4 b2 = B4[(4 * kk + 2) * 16 + l];
        float4 b3 = B4[(4 * kk + 3) * 16 + l];
#pragma unroll
        for (int r = 0; r < 8; ++r) {
            float4 a = ((const float4*)(As + (g * 8 + r) * K))[kk];
            acc[r][0] = fmaf(a.x, b0.x, fmaf(a.y, b1.x, fmaf(a.z, b2.x, fmaf(a.w, b3.x, acc[r][0]))));
            acc[r][1] = fmaf(a.x, b0.y, fmaf(a.y, b1.y, fmaf(a.z, b2.y, fmaf(a.w, b3.y, acc[r][1]))));
            acc[r][2] = fmaf(a.x, b0.z, fmaf(a.y, b1.z, fmaf(a.z, b2.z, fmaf(a.w, b3.z, acc[r][2]))));
            acc[r][3] = fmaf(a.x, b0.w, fmaf(a.y, b1.w, fmaf(a.z, b2.w, fmaf(a.w, b3.w, acc[r][3]))));
        }
    }
    if (EPI == 2) {
        uint2* C = (uint2*)Cv;
        float al0 = aux[4 * l], al1 = aux[4 * l + 1], al2 = aux[4 * l + 2], al3 = aux[4 * l + 3];
        float ar0 = aux[64 + 4 * l], ar1 = aux[64 + 4 * l + 1], ar2 = aux[64 + 4 * l + 2], ar3 = aux[64 + 4 * l + 3];
#pragma unroll
        for (int r = 0; r < 8; ++r) {
            int row = m0 + g * 8 + r;
            float pl = acc[r][0] * al0 + acc[r][1] * al1 + acc[r][2] * al2 + acc[r][3] * al3;
            float pr = acc[r][0] * ar0 + acc[r][1] * ar1 + acc[r][2] * ar2 + acc[r][3] * ar3;
#pragma unroll
            for (int mask = 8; mask; mask >>= 1) { pl += __shfl_xor(pl, mask); pr += __shfl_xor(pr, mask); }
            if (row < N_NODES) {
                uint2 v; v.x = pack2(acc[r][0], acc[r][1]); v.y = pack2(acc[r][2], acc[r][3]);
                C[(size_t)row * 16 + l] = v;
                if (l == 0) { es[row] = pl; ed[row] = pr; }
            }
        }
    } else {
        float4* C = (float4*)Cv;
        float4 bv = ((const float4*)aux)[l];
#pragma unroll
        for (int r = 0; r < 8; ++r) {
            int row = m0 + g * 8 + r;
            if (row < N_NODES) {
                float4 v;
                v.x = acc[r][0] + bv.x; v.y = acc[r][1] + bv.y;
                v.z = acc[r][2] + bv.z; v.w = acc[r][3] + bv.w;
                C[(size_t)row * 16 + l] = v;
            }
        }
    }
}

// ---------------- layer-1 fused softmax+aggregate: one wave per node ----------------
__global__ void k_agg1(const unsigned* __restrict__ h1b, const float* __restrict__ es,
                       const float* __restrict__ ed, const int* __restrict__ off,
                       const unsigned short* __restrict__ srcs, float* __restrict__ out1) {
    int n = blockIdx.x * (blockDim.x >> 6) + (threadIdx.x >> 6);
    int lane = threadIdx.x & 63;
    if (n >= N_NODES) return;
    int myh = lane & 3;
    float edh = ed[n * 4 + myh];
    int hc = lane >> 4;
    int s = off[n], e = off[n + 1];
    int jj = lane >> 2;
    float ax = 0.f, ay = 0.f, psum = 0.f;
    for (int base = s; base < e; base += 16) {
        int cnt = e - base;
        int srcj = 0;
        float w = 0.f;
        if (jj < cnt) {
            srcj = srcs[base + jj];
            w = __expf(lrelu(es[srcj * 4 + myh] + edh));
        }
        psum += w;
        unsigned pv[16];
        float wv[16];
#pragma unroll
        for (int j2 = 0; j2 < 16; ++j2) {
            int src = __shfl(srcj, j2 * 4);
            wv[j2] = __shfl(w, j2 * 4 + hc);
            pv[j2] = h1b[(size_t)src * 64 + lane];
        }
#pragma unroll
        for (int j2 = 0; j2 < 16; ++j2) {
            ax = fmaf(bflo(pv[j2]), wv[j2], ax);
            ay = fmaf(bfhi(pv[j2]), wv[j2], ay);
        }
    }
#pragma unroll
    for (int mask = 4; mask <= 32; mask <<= 1) psum += __shfl_xor(psum, mask);
    float inv = 1.f / __shfl(psum, hc);
    float2 o;
    o.x = fmaxf(ax * inv, 0.f);
    o.y = fmaxf(ay * inv, 0.f);
    ((float2*)out1)[(size_t)n * 64 + lane] = o;
}

// ---------------- layer-2 fused softmax+aggregate: half-wave per node ----------------
__global__ void k_agg2(const unsigned* __restrict__ h2b, const float* __restrict__ es,
                       const float* __restrict__ ed, const int* __restrict__ off,
                       const unsigned short* __restrict__ srcs, float* __restrict__ outv) {
    int n = blockIdx.x * (blockDim.x >> 5) + (threadIdx.x >> 5);
    int l = threadIdx.x & 31;
    int hb = threadIdx.x & 32;
    if (n >= N_NODES) return;
    float edv = ed[n];
    int s = off[n], e = off[n + 1];
    const uint2* gp = (const uint2*)h2b;
    int l16 = l & 15;
    int sb0 = (l >> 4) * 2;
    float a0 = 0.f, a1 = 0.f, a2 = 0.f, a3 = 0.f, psum = 0.f;
    for (int base = s; base < e; base += 32) {
        int cnt = e - base;
        int srcj = 0;
        float w = 0.f;
        if (l < cnt) {
            srcj = srcs[base + l];
            w = __expf(lrelu(es[srcj] + edv));
        }
        psum += w;
#pragma unroll
        for (int sub = 0; sub < 2; ++sub) {
            uint2 pv[8];
            float wv[8];
#pragma unroll
            for (int j = 0; j < 8; ++j) {
                int lsrc = hb + (sb0 + sub) * 8 + j;
                int src = __shfl(srcj, lsrc);
                wv[j] = __shfl(w, lsrc);
                pv[j] = gp[(size_t)src * 16 + l16];
            }
#pragma unroll
            for (int j = 0; j < 8; ++j) {
                a0 = fmaf(bflo(pv[j].x), wv[j], a0);
                a1 = fmaf(bfhi(pv[j].x), wv[j], a1);
                a2 = fmaf(bflo(pv[j].y), wv[j], a2);
                a3 = fmaf(bfhi(pv[j].y), wv[j], a3);
            }
        }
    }
#pragma unroll
    for (int mask = 1; mask <= 16; mask <<= 1) psum += __shfl_xor(psum, mask);
    float inv = 1.f / psum;
    a0 += __shfl_xor(a0, 16); a1 += __shfl_xor(a1, 16);
    a2 += __shfl_xor(a2, 16); a3 += __shfl_xor(a3, 16);
    if (l < 16) {
        float4 o;
        o.x = a0 * inv; o.y = a1 * inv; o.z = a2 * inv; o.w = a3 * inv;
        ((float4*)outv)[(size_t)n * 16 + l16] = o;
    }
}

extern "C" void kernel_launch(void* const* d_in, const int* in_sizes, int n_in,
                              void* d_out, int out_size, void* d_ws, size_t ws_size,
                              hipStream_t stream) {
    const float* x     = (const float*)d_in[0];
    const int*   ei    = (const int*)d_in[1];
    const float* W1    = (const float*)d_in[2];
    const float* attn1 = (const float*)d_in[3];
    const float* W2    = (const float*)d_in[4];
    const float* attn2 = (const float*)d_in[5];
    const float* headW = (const float*)d_in[6];
    const float* headb = (const float*)d_in[7];
    float* out = (float*)d_out;

    char* ws = (char*)d_ws;
    size_t o = 0;
    auto alloc = [&](size_t bytes) -> void* {
        o = (o + 255) & ~(size_t)255;
        void* p = ws + o;
        o += bytes;
        return p;
    };
    unsigned*       h1b    = (unsigned*)alloc((size_t)N_NODES * 128 * 2);
    float*          out1   = (float*)alloc((size_t)N_NODES * 128 * 4);
    unsigned*       h2b    = (unsigned*)alloc((size_t)N_NODES * 64 * 2);
    float*          h2agg  = (float*)alloc((size_t)N_NODES * 64 * 4);
    float*          e1s    = (float*)alloc((size_t)N_NODES * 4 * 4);
    float*          e1d    = (float*)alloc((size_t)N_NODES * 4 * 4);
    float*          e2s    = (float*)alloc((size_t)N_NODES * 4);
    float*          e2d    = (float*)alloc((size_t)N_NODES * 4);
    int*            deg    = (int*)alloc((size_t)N_NODES * 4);
    int*            off    = (int*)alloc((size_t)(N_NODES + 1) * 4);
    unsigned short* rank   = (unsigned short*)alloc((size_t)E_TOT * 2);
    unsigned short* srcs   = (unsigned short*)alloc((size_t)E_TOT * 2);
    int*            blksum = (int*)alloc((size_t)NBLK * 4);
    int*            blkoff = (int*)alloc((size_t)NBLK * 4);
    unsigned*       Btg    = (unsigned*)alloc((size_t)128 * 64 * 4);  // W1^T bf16

    // prep W1 transpose (32KB, stays hot in L2 for all gemm blocks)
    k_prepB<<<128, 64, 0, stream>>>(W1, Btg);

    // fused: gemm1 MFMA (+attn1 epilogue) || deg_rank histogram
    (void)hipMemsetAsync(deg, 0, (size_t)N_NODES * 4, stream);
    k_gemm1_deg<<<G1_BLOCKS + G2_BLOCKS, 256, 0, stream>>>(
        x, Btg, attn1, (uint2*)h1b, e1s, e1d, ei, deg, rank);

    // CSR finalize
    k_scan1<<<NBLK, 1024, 0, stream>>>(deg, off, blksum);
    k_scan2<<<1, 64, 0, stream>>>(blksum, blkoff, off);
    k_scan3<<<(N_NODES + 255) / 256, 256, 0, stream>>>(off, blkoff);
    k_scatter2<<<(E_TOT / 4 + 255) / 256, 256, 0, stream>>>(ei, off, rank, srcs);

    // layer 1 aggregate
    k_agg1<<<N_NODES / 4, 256, 0, stream>>>(h1b, e1s, e1d, off, srcs, out1);

    // layer 2
    k_gemm23<128, 2><<<(N_NODES + 31) / 32, 64, 0, stream>>>(out1, W2, attn2, h2b, e2s, e2d);
    k_agg2<<<N_NODES / 8, 256, 0, stream>>>(h2b, e2s, e2d, off, srcs, h2agg);

    // head
    k_gemm23<64, 3><<<(N_NODES + 31) / 32, 64, 0, stream>>>(h2agg, headW, headb, out, nullptr, nullptr);
}

// Round 2
// 238.454 us; speedup vs baseline: 1.1384x; 1.1006x over previous
//
#include <hip/hip_runtime.h>
#include <math.h>

#define N_NODES 50000
#define E_RAW 800000
#define E_TOT 850000
#define NEG_SLOPE 0.2f
#define G1_BLOCKS ((N_NODES + 63) / 64)          // gemm1 MFMA part: BM=64, 256 thr
#define NBUCK 391                                // ceil(50000 / 128) col-buckets
#define EPB 2048                                 // edges per partition block
#define PBLK ((E_TOT + EPB - 1) / EPB)           // 416 partition blocks

typedef __attribute__((ext_vector_type(8))) short bf16x8;
typedef __attribute__((ext_vector_type(4))) float f32x4;

__device__ __forceinline__ float lrelu(float a) { return a > 0.f ? a : NEG_SLOPE * a; }

__device__ __forceinline__ unsigned f2bf(float f) {
    unsigned u = __float_as_uint(f);
    return (u + 0x7fff + ((u >> 16) & 1)) >> 16;
}
__device__ __forceinline__ unsigned pack2(float a, float b) {
    return f2bf(a) | (f2bf(b) << 16);
}
__device__ __forceinline__ float bflo(unsigned p) { return __uint_as_float(p << 16); }
__device__ __forceinline__ float bfhi(unsigned p) { return __uint_as_float(p & 0xffff0000u); }

// ---------------- prep: W1 (128x128 fp32 row-major) -> Btg[col][k] bf16 ----------------
__global__ void k_prepB(const float* __restrict__ W, unsigned* __restrict__ Btg) {
    int c = blockIdx.x;            // 0..127 output column of W1
    int tq = threadIdx.x;          // 0..63  word = k/2
    float a = W[(2 * tq) * 128 + c];
    float b = W[(2 * tq + 1) * 128 + c];
    Btg[c * 64 + tq] = pack2(a, b);
}

// ---------------- FUSED: gemm1 MFMA (blocks < G1) || P1 bucket histogram ----------------
// gemm1: h1 = x @ W1 via v_mfma_f32_16x16x32_bf16 (unchanged from last round).
// P1: per-2048-edge block LDS histogram over 391 col-buckets (col>>7) -> hist2d[bucket][blk].
//     NO global atomics (the old 850K device-scope atomicAdds were the 55us floor).
__global__ void k_gemm1_p1(const float* __restrict__ A, const unsigned* __restrict__ Btg,
                           const float* __restrict__ aux, uint2* __restrict__ C,
                           float* __restrict__ es, float* __restrict__ ed,
                           const int* __restrict__ ei, int* __restrict__ hist2d) {
    __shared__ unsigned As[64 * 64];   // 16 KB (gemm tile; P1 reuses first 1.6KB as int hist)
    if (blockIdx.x >= G1_BLOCKS) {
        // ---- P1 body: bucket histogram, LDS atomics only ----
        int blk = blockIdx.x - G1_BLOCKS;
        int* h = (int*)As;
        for (int i = threadIdx.x; i < NBUCK; i += 256) h[i] = 0;
        __syncthreads();
        int base = blk * EPB;
        for (int i = threadIdx.x; i < EPB; i += 256) {
            int e = base + i;
            if (e >= E_TOT) break;
            int col = (e < E_RAW) ? ei[E_RAW + e] : (e - E_RAW);
            atomicAdd(&h[col >> 7], 1);
        }
        __syncthreads();
        for (int i = threadIdx.x; i < NBUCK; i += 256) hist2d[i * PBLK + blk] = h[i];
        return;
    }
    // ---- gemm1 MFMA body ----
    int t = threadIdx.x;
    int m0 = blockIdx.x * 64;
    int rows = min(64, N_NODES - m0);
    const float4* A4 = (const float4*)(A + (size_t)m0 * 128);
    for (int i = t; i < rows * 32; i += 256) {
        int row = i >> 5, k4 = i & 31;
        float4 v = A4[i];
        int byte = (k4 * 8) ^ ((row & 7) << 4);
        unsigned* p = &As[row * 64 + (byte >> 2)];
        p[0] = pack2(v.x, v.y);
        p[1] = pack2(v.z, v.w);
    }
    __syncthreads();
    int lane = t & 63, wave = t >> 6;
    int r15 = lane & 15, g = lane >> 4;
    int arow = wave * 16 + r15;
    f32x4 acc[8];
#pragma unroll
    for (int i = 0; i < 8; ++i) acc[i] = (f32x4){0.f, 0.f, 0.f, 0.f};
    const char* Abase = (const char*)As + arow * 256;
    int swz = (arow & 7) << 4;
    const char* Bbase = (const char*)Btg;
#pragma unroll
    for (int s = 0; s < 4; ++s) {
        bf16x8 xf = *(const bf16x8*)(Abase + ((64 * s + 16 * g) ^ swz));
#pragma unroll
        for (int tt = 0; tt < 8; ++tt) {
            bf16x8 wf = *(const bf16x8*)(Bbase + ((16 * tt + r15) * 256 + 64 * s + 16 * g));
            acc[tt] = __builtin_amdgcn_mfma_f32_16x16x32_bf16(wf, xf, acc[tt], 0, 0, 0);
        }
    }
    int grow = m0 + arow;
    bool valid = (arow < rows);
    if (valid) {
        uint2* C2 = C + (size_t)grow * 32;
#pragma unroll
        for (int tt = 0; tt < 8; ++tt) {
            uint2 v; v.x = pack2(acc[tt][0], acc[tt][1]); v.y = pack2(acc[tt][2], acc[tt][3]);
            C2[4 * tt + g] = v;
        }
    }
    float ps0 = 0.f, ps1 = 0.f, ps2 = 0.f, ps3 = 0.f;
    float pd0 = 0.f, pd1 = 0.f, pd2 = 0.f, pd3 = 0.f;
#pragma unroll
    for (int tt = 0; tt < 8; ++tt) {
        int h = tt >> 1;
        int fin = 16 * (tt & 1) + 4 * g;
        float4 alv = *(const float4*)(aux + h * 64 + fin);
        float4 arv = *(const float4*)(aux + h * 64 + 32 + fin);
        float s4 = acc[tt][0] * alv.x + acc[tt][1] * alv.y + acc[tt][2] * alv.z + acc[tt][3] * alv.w;
        float d4 = acc[tt][0] * arv.x + acc[tt][1] * arv.y + acc[tt][2] * arv.z + acc[tt][3] * arv.w;
        if (h == 0) { ps0 += s4; pd0 += d4; }
        else if (h == 1) { ps1 += s4; pd1 += d4; }
        else if (h == 2) { ps2 += s4; pd2 += d4; }
        else { ps3 += s4; pd3 += d4; }
    }
#pragma unroll
    for (int mask = 16; mask <= 32; mask <<= 1) {
        ps0 += __shfl_xor(ps0, mask); ps1 += __shfl_xor(ps1, mask);
        ps2 += __shfl_xor(ps2, mask); ps3 += __shfl_xor(ps3, mask);
        pd0 += __shfl_xor(pd0, mask); pd1 += __shfl_xor(pd1, mask);
        pd2 += __shfl_xor(pd2, mask); pd3 += __shfl_xor(pd3, mask);
    }
    if (valid) {
        float psg = (g == 0) ? ps0 : (g == 1) ? ps1 : (g == 2) ? ps2 : ps3;
        float pdg = (g == 0) ? pd0 : (g == 1) ? pd1 : (g == 2) ? pd2 : pd3;
        es[grow * 4 + g] = psg;
        ed[grow * 4 + g] = pdg;
    }
}

// ---------------- P2a: per-bucket scan over partition blocks ----------------
// off2d[b][blk] = exclusive prefix of hist2d[b][*]; bucktot[b] = total.
__global__ void k_p2a(const int* __restrict__ hist2d, int* __restrict__ off2d,
                      int* __restrict__ bucktot) {
    __shared__ int sh[512];
    int b = blockIdx.x, t = threadIdx.x;
    int v = (t < PBLK) ? hist2d[b * PBLK + t] : 0;
    sh[t] = v;
    __syncthreads();
    for (int ofs = 1; ofs < 512; ofs <<= 1) {
        int u = (t >= ofs) ? sh[t - ofs] : 0;
        __syncthreads();
        sh[t] += u;
        __syncthreads();
    }
    if (t < PBLK) off2d[b * PBLK + t] = sh[t] - v;
    if (t == 511) bucktot[b] = sh[511];
}

// ---------------- P2b: scan bucket totals -> bucketbase ----------------
__global__ void k_p2b(const int* __restrict__ bucktot, int* __restrict__ bucketbase) {
    __shared__ int sh[512];
    int t = threadIdx.x;
    int v = (t < NBUCK) ? bucktot[t] : 0;
    sh[t] = v;
    __syncthreads();
    for (int ofs = 1; ofs < 512; ofs <<= 1) {
        int u = (t >= ofs) ? sh[t - ofs] : 0;
        __syncthreads();
        sh[t] += u;
        __syncthreads();
    }
    if (t < NBUCK) bucketbase[t] = sh[t] - v;
    if (t == 511) bucketbase[NBUCK] = sh[511];
}

// ---------------- P3: partition edges into bucket-grouped part[] ----------------
// part[pos] = src | (col&127)<<16, pos = bucketbase[b] + off2d[b][blk] + LDS-local rank.
__global__ void k_p3(const int* __restrict__ ei, const int* __restrict__ off2d,
                     const int* __restrict__ bucketbase, unsigned* __restrict__ part) {
    __shared__ int h[NBUCK];
    __shared__ int basebuf[NBUCK];
    int blk = blockIdx.x, t = threadIdx.x;
    for (int i = t; i < NBUCK; i += 256) {
        h[i] = 0;
        basebuf[i] = bucketbase[i] + off2d[i * PBLK + blk];
    }
    __syncthreads();
    int base = blk * EPB;
    for (int i = t; i < EPB; i += 256) {
        int e = base + i;
        if (e >= E_TOT) break;
        int col, src;
        if (e < E_RAW) { col = ei[E_RAW + e]; src = ei[e]; }
        else { col = src = e - E_RAW; }
        int b = col >> 7;
        int lr = atomicAdd(&h[b], 1);
        part[basebuf[b] + lr] = (unsigned)src | ((unsigned)(col & 127) << 16);
    }
}

// ---------------- P4: per-bucket col histogram + scan -> off[] and srcs[] ----------------
__global__ void k_p4(const unsigned* __restrict__ part, const int* __restrict__ bucketbase,
                     int* __restrict__ off, unsigned short* __restrict__ srcs) {
    __shared__ int h[128];
    __shared__ int colofs[128];
    int b = blockIdx.x, t = threadIdx.x;
    int s0 = bucketbase[b], s1 = bucketbase[b + 1];
    if (t < 128) h[t] = 0;
    __syncthreads();
    for (int i = s0 + t; i < s1; i += 256) atomicAdd(&h[part[i] >> 16], 1);
    __syncthreads();
    if (t == 0) {
        int acc = 0;
        for (int c = 0; c < 128; ++c) { colofs[c] = acc; acc += h[c]; }
    }
    __syncthreads();
    int colbase = b * 128, ncols = min(128, N_NODES - colbase);
    if (t < ncols) off[colbase + t] = s0 + colofs[t];
    if (b == NBUCK - 1 && t == 0) off[N_NODES] = s1;
    if (t < 128) h[t] = colofs[t];     // reuse as cursors
    __syncthreads();
    for (int i = s0 + t; i < s1; i += 256) {
        unsigned u = part[i];
        int c = u >> 16;
        int slot = atomicAdd(&h[c], 1);
        srcs[s0 + slot] = (unsigned short)(u & 0xffffu);
    }
}

// ---------------- GEMM 2/3: NC=64 (unchanged this round) ----------------
template<int K, int EPI>
__global__ void k_gemm23(const float* __restrict__ A, const float* __restrict__ B,
                         const float* __restrict__ aux, void* __restrict__ Cv,
                         float* __restrict__ es, float* __restrict__ ed) {
    constexpr int MT = 32;
    __shared__ float As[MT * K];
    int m0 = blockIdx.x * MT;
    int t = threadIdx.x, g = t >> 4, l = t & 15;
    int rows = min(MT, N_NODES - m0);
    const float4* A4 = (const float4*)(A + (size_t)m0 * K);
    float4* S4 = (float4*)As;
    for (int i = t; i < rows * (K / 4); i += 64) S4[i] = A4[i];
    __syncthreads();
    float acc[8][4];
#pragma unroll
    for (int r = 0; r < 8; ++r)
#pragma unroll
        for (int c = 0; c < 4; ++c) acc[r][c] = 0.f;
    const float4* B4 = (const float4*)B;   // row k = 16 float4
    for (int kk = 0; kk < K / 4; ++kk) {
        float4 b0 = B4[(4 * kk + 0) * 16 + l];
        float4 b1 = B4[(4 * kk + 1) * 16 + l];
        float4 b2 = B4[(4 * kk + 2) * 16 + l];
        float4 b3 = B4[(4 * kk + 3) * 16 + l];
#pragma unroll
        for (int r = 0; r < 8; ++r) {
            float4 a = ((const float4*)(As + (g * 8 + r) * K))[kk];
            acc[r][0] = fmaf(a.x, b0.x, fmaf(a.y, b1.x, fmaf(a.z, b2.x, fmaf(a.w, b3.x, acc[r][0]))));
            acc[r][1] = fmaf(a.x, b0.y, fmaf(a.y, b1.y, fmaf(a.z, b2.y, fmaf(a.w, b3.y, acc[r][1]))));
            acc[r][2] = fmaf(a.x, b0.z, fmaf(a.y, b1.z, fmaf(a.z, b2.z, fmaf(a.w, b3.z, acc[r][2]))));
            acc[r][3] = fmaf(a.x, b0.w, fmaf(a.y, b1.w, fmaf(a.z, b2.w, fmaf(a.w, b3.w, acc[r][3]))));
        }
    }
    if (EPI == 2) {
        uint2* C = (uint2*)Cv;
        float al0 = aux[4 * l], al1 = aux[4 * l + 1], al2 = aux[4 * l + 2], al3 = aux[4 * l + 3];
        float ar0 = aux[64 + 4 * l], ar1 = aux[64 + 4 * l + 1], ar2 = aux[64 + 4 * l + 2], ar3 = aux[64 + 4 * l + 3];
#pragma unroll
        for (int r = 0; r < 8; ++r) {
            int row = m0 + g * 8 + r;
            float pl = acc[r][0] * al0 + acc[r][1] * al1 + acc[r][2] * al2 + acc[r][3] * al3;
            float pr = acc[r][0] * ar0 + acc[r][1] * ar1 + acc[r][2] * ar2 + acc[r][3] * ar3;
#pragma unroll
            for (int mask = 8; mask; mask >>= 1) { pl += __shfl_xor(pl, mask); pr += __shfl_xor(pr, mask); }
            if (row < N_NODES) {
                uint2 v; v.x = pack2(acc[r][0], acc[r][1]); v.y = pack2(acc[r][2], acc[r][3]);
                C[(size_t)row * 16 + l] = v;
                if (l == 0) { es[row] = pl; ed[row] = pr; }
            }
        }
    } else {
        float4* C = (float4*)Cv;
        float4 bv = ((const float4*)aux)[l];
#pragma unroll
        for (int r = 0; r < 8; ++r) {
            int row = m0 + g * 8 + r;
            if (row < N_NODES) {
                float4 v;
                v.x = acc[r][0] + bv.x; v.y = acc[r][1] + bv.y;
                v.z = acc[r][2] + bv.z; v.w = acc[r][3] + bv.w;
                C[(size_t)row * 16 + l] = v;
            }
        }
    }
}

// ---------------- layer-1 fused softmax+aggregate: one wave per node ----------------
__global__ void k_agg1(const unsigned* __restrict__ h1b, const float* __restrict__ es,
                       const float* __restrict__ ed, const int* __restrict__ off,
                       const unsigned short* __restrict__ srcs, float* __restrict__ out1) {
    int n = blockIdx.x * (blockDim.x >> 6) + (threadIdx.x >> 6);
    int lane = threadIdx.x & 63;
    if (n >= N_NODES) return;
    int myh = lane & 3;
    float edh = ed[n * 4 + myh];
    int hc = lane >> 4;
    int s = off[n], e = off[n + 1];
    int jj = lane >> 2;
    float ax = 0.f, ay = 0.f, psum = 0.f;
    for (int base = s; base < e; base += 16) {
        int cnt = e - base;
        int srcj = 0;
        float w = 0.f;
        if (jj < cnt) {
            srcj = srcs[base + jj];
            w = __expf(lrelu(es[srcj * 4 + myh] + edh));
        }
        psum += w;
        unsigned pv[16];
        float wv[16];
#pragma unroll
        for (int j2 = 0; j2 < 16; ++j2) {
            int src = __shfl(srcj, j2 * 4);
            wv[j2] = __shfl(w, j2 * 4 + hc);
            pv[j2] = h1b[(size_t)src * 64 + lane];
        }
#pragma unroll
        for (int j2 = 0; j2 < 16; ++j2) {
            ax = fmaf(bflo(pv[j2]), wv[j2], ax);
            ay = fmaf(bfhi(pv[j2]), wv[j2], ay);
        }
    }
#pragma unroll
    for (int mask = 4; mask <= 32; mask <<= 1) psum += __shfl_xor(psum, mask);
    float inv = 1.f / __shfl(psum, hc);
    float2 o;
    o.x = fmaxf(ax * inv, 0.f);
    o.y = fmaxf(ay * inv, 0.f);
    ((float2*)out1)[(size_t)n * 64 + lane] = o;
}

// ---------------- layer-2 fused softmax+aggregate: half-wave per node ----------------
__global__ void k_agg2(const unsigned* __restrict__ h2b, const float* __restrict__ es,
                       const float* __restrict__ ed, const int* __restrict__ off,
                       const unsigned short* __restrict__ srcs, float* __restrict__ outv) {
    int n = blockIdx.x * (blockDim.x >> 5) + (threadIdx.x >> 5);
    int l = threadIdx.x & 31;
    int hb = threadIdx.x & 32;
    if (n >= N_NODES) return;
    float edv = ed[n];
    int s = off[n], e = off[n + 1];
    const uint2* gp = (const uint2*)h2b;
    int l16 = l & 15;
    int sb0 = (l >> 4) * 2;
    float a0 = 0.f, a1 = 0.f, a2 = 0.f, a3 = 0.f, psum = 0.f;
    for (int base = s; base < e; base += 32) {
        int cnt = e - base;
        int srcj = 0;
        float w = 0.f;
        if (l < cnt) {
            srcj = srcs[base + l];
            w = __expf(lrelu(es[srcj] + edv));
        }
        psum += w;
#pragma unroll
        for (int sub = 0; sub < 2; ++sub) {
            uint2 pv[8];
            float wv[8];
#pragma unroll
            for (int j = 0; j < 8; ++j) {
                int lsrc = hb + (sb0 + sub) * 8 + j;
                int src = __shfl(srcj, lsrc);
                wv[j] = __shfl(w, lsrc);
                pv[j] = gp[(size_t)src * 16 + l16];
            }
#pragma unroll
            for (int j = 0; j < 8; ++j) {
                a0 = fmaf(bflo(pv[j].x), wv[j], a0);
                a1 = fmaf(bfhi(pv[j].x), wv[j], a1);
                a2 = fmaf(bflo(pv[j].y), wv[j], a2);
                a3 = fmaf(bfhi(pv[j].y), wv[j], a3);
            }
        }
    }
#pragma unroll
    for (int mask = 1; mask <= 16; mask <<= 1) psum += __shfl_xor(psum, mask);
    float inv = 1.f / psum;
    a0 += __shfl_xor(a0, 16); a1 += __shfl_xor(a1, 16);
    a2 += __shfl_xor(a2, 16); a3 += __shfl_xor(a3, 16);
    if (l < 16) {
        float4 o;
        o.x = a0 * inv; o.y = a1 * inv; o.z = a2 * inv; o.w = a3 * inv;
        ((float4*)outv)[(size_t)n * 16 + l16] = o;
    }
}

extern "C" void kernel_launch(void* const* d_in, const int* in_sizes, int n_in,
                              void* d_out, int out_size, void* d_ws, size_t ws_size,
                              hipStream_t stream) {
    const float* x     = (const float*)d_in[0];
    const int*   ei    = (const int*)d_in[1];
    const float* W1    = (const float*)d_in[2];
    const float* attn1 = (const float*)d_in[3];
    const float* W2    = (const float*)d_in[4];
    const float* attn2 = (const float*)d_in[5];
    const float* headW = (const float*)d_in[6];
    const float* headb = (const float*)d_in[7];
    float* out = (float*)d_out;

    char* ws = (char*)d_ws;
    size_t o = 0;
    auto alloc = [&](size_t bytes) -> void* {
        o = (o + 255) & ~(size_t)255;
        void* p = ws + o;
        o += bytes;
        return p;
    };
    unsigned*       h1b    = (unsigned*)alloc((size_t)N_NODES * 128 * 2);
    float*          out1   = (float*)alloc((size_t)N_NODES * 128 * 4);
    unsigned*       h2b    = (unsigned*)alloc((size_t)N_NODES * 64 * 2);
    float*          h2agg  = (float*)alloc((size_t)N_NODES * 64 * 4);
    float*          e1s    = (float*)alloc((size_t)N_NODES * 4 * 4);
    float*          e1d    = (float*)alloc((size_t)N_NODES * 4 * 4);
    float*          e2s    = (float*)alloc((size_t)N_NODES * 4);
    float*          e2d    = (float*)alloc((size_t)N_NODES * 4);
    int*            off    = (int*)alloc((size_t)(N_NODES + 1) * 4);
    unsigned short* srcs   = (unsigned short*)alloc((size_t)E_TOT * 2);
    unsigned*       Btg    = (unsigned*)alloc((size_t)128 * 64 * 4);   // W1^T bf16
    int*            hist2d = (int*)alloc((size_t)NBUCK * PBLK * 4);    // [bucket][blk]
    int*            off2d  = (int*)alloc((size_t)NBUCK * PBLK * 4);
    int*            bucktot = (int*)alloc((size_t)NBUCK * 4);
    int*            bucketbase = (int*)alloc((size_t)(NBUCK + 1) * 4);
    unsigned*       part   = (unsigned*)alloc((size_t)E_TOT * 4);      // src | collow<<16

    // prep W1 transpose (32KB, stays hot in L2 for all gemm blocks)
    k_prepB<<<128, 64, 0, stream>>>(W1, Btg);

    // fused: gemm1 MFMA (+attn1 epilogue) || P1 bucket histogram (LDS atomics only)
    k_gemm1_p1<<<G1_BLOCKS + PBLK, 256, 0, stream>>>(
        x, Btg, attn1, (uint2*)h1b, e1s, e1d, ei, hist2d);

    // CSR build: scans + partition + per-bucket finalize (no global atomics anywhere)
    k_p2a<<<NBUCK, 512, 0, stream>>>(hist2d, off2d, bucktot);
    k_p2b<<<1, 512, 0, stream>>>(bucktot, bucketbase);
    k_p3<<<PBLK, 256, 0, stream>>>(ei, off2d, bucketbase, part);
    k_p4<<<NBUCK, 256, 0, stream>>>(part, bucketbase, off, srcs);

    // layer 1 aggregate
    k_agg1<<<N_NODES / 4, 256, 0, stream>>>(h1b, e1s, e1d, off, srcs, out1);

    // layer 2
    k_gemm23<128, 2><<<(N_NODES + 31) / 32, 64, 0, stream>>>(out1, W2, attn2, h2b, e2s, e2d);
    k_agg2<<<N_NODES / 8, 256, 0, stream>>>(h2b, e2s, e2d, off, srcs, h2agg);

    // head
    k_gemm23<64, 3><<<(N_NODES + 31) / 32, 64, 0, stream>>>(h2agg, headW, headb, out, nullptr, nullptr);
}

// Round 3
// 222.418 us; speedup vs baseline: 1.2204x; 1.0721x over previous
//
#include <hip/hip_runtime.h>
#include <math.h>

#define N_NODES 50000
#define E_RAW 800000
#define E_TOT 850000
#define NEG_SLOPE 0.2f
#define G1_BLOCKS ((N_NODES + 63) / 64)          // gemm1 MFMA part: BM=64, 256 thr
#define NBUCK 391                                // ceil(50000 / 128) col-buckets
#define EPB 2048                                 // edges per partition block
#define PBLK ((E_TOT + EPB - 1) / EPB)           // 416 partition blocks

typedef __attribute__((ext_vector_type(8))) short bf16x8;
typedef __attribute__((ext_vector_type(4))) float f32x4;

__device__ __forceinline__ float lrelu(float a) { return a > 0.f ? a : NEG_SLOPE * a; }

__device__ __forceinline__ unsigned f2bf(float f) {
    unsigned u = __float_as_uint(f);
    return (u + 0x7fff + ((u >> 16) & 1)) >> 16;
}
__device__ __forceinline__ unsigned pack2(float a, float b) {
    return f2bf(a) | (f2bf(b) << 16);
}
__device__ __forceinline__ float bflo(unsigned p) { return __uint_as_float(p << 16); }
__device__ __forceinline__ float bfhi(unsigned p) { return __uint_as_float(p & 0xffff0000u); }

// ---------------- prep: W1 (128x128) -> Btg[col][k] bf16 ; W2 (128x64) -> B2tg[col][k] ----------------
__global__ void k_prep(const float* __restrict__ W1, const float* __restrict__ W2,
                       unsigned* __restrict__ Btg, unsigned* __restrict__ B2tg) {
    int c = blockIdx.x;            // 0..127: W1 col; 128..191: W2 col
    int tq = threadIdx.x;          // 0..63  word = k/2
    if (c < 128) {
        Btg[c * 64 + tq] = pack2(W1[(2 * tq) * 128 + c], W1[(2 * tq + 1) * 128 + c]);
    } else {
        int c2 = c - 128;
        B2tg[c2 * 64 + tq] = pack2(W2[(2 * tq) * 64 + c2], W2[(2 * tq + 1) * 64 + c2]);
    }
}

// ---------------- FUSED: gemm1 MFMA (blocks < G1) || P1 bucket histogram ----------------
__global__ void k_gemm1_p1(const float* __restrict__ A, const unsigned* __restrict__ Btg,
                           const float* __restrict__ aux, uint2* __restrict__ C,
                           float* __restrict__ es, float* __restrict__ ed,
                           const int* __restrict__ ei, int* __restrict__ hist2d) {
    __shared__ unsigned As[64 * 64];   // 16 KB (gemm tile; P1 reuses first 1.6KB as int hist)
    if (blockIdx.x >= G1_BLOCKS) {
        // ---- P1 body: bucket histogram, LDS atomics only ----
        int blk = blockIdx.x - G1_BLOCKS;
        int* h = (int*)As;
        for (int i = threadIdx.x; i < NBUCK; i += 256) h[i] = 0;
        __syncthreads();
        int base = blk * EPB;
        for (int i = threadIdx.x; i < EPB; i += 256) {
            int e = base + i;
            if (e >= E_TOT) break;
            int col = (e < E_RAW) ? ei[E_RAW + e] : (e - E_RAW);
            atomicAdd(&h[col >> 7], 1);
        }
        __syncthreads();
        for (int i = threadIdx.x; i < NBUCK; i += 256) hist2d[i * PBLK + blk] = h[i];
        return;
    }
    // ---- gemm1 MFMA body ----
    int t = threadIdx.x;
    int m0 = blockIdx.x * 64;
    int rows = min(64, N_NODES - m0);
    const float4* A4 = (const float4*)(A + (size_t)m0 * 128);
    for (int i = t; i < rows * 32; i += 256) {
        int row = i >> 5, k4 = i & 31;
        float4 v = A4[i];
        int byte = (k4 * 8) ^ ((row & 7) << 4);
        unsigned* p = &As[row * 64 + (byte >> 2)];
        p[0] = pack2(v.x, v.y);
        p[1] = pack2(v.z, v.w);
    }
    __syncthreads();
    int lane = t & 63, wave = t >> 6;
    int r15 = lane & 15, g = lane >> 4;
    int arow = wave * 16 + r15;
    f32x4 acc[8];
#pragma unroll
    for (int i = 0; i < 8; ++i) acc[i] = (f32x4){0.f, 0.f, 0.f, 0.f};
    const char* Abase = (const char*)As + arow * 256;
    int swz = (arow & 7) << 4;
    const char* Bbase = (const char*)Btg;
#pragma unroll
    for (int s = 0; s < 4; ++s) {
        bf16x8 xf = *(const bf16x8*)(Abase + ((64 * s + 16 * g) ^ swz));
#pragma unroll
        for (int tt = 0; tt < 8; ++tt) {
            bf16x8 wf = *(const bf16x8*)(Bbase + ((16 * tt + r15) * 256 + 64 * s + 16 * g));
            acc[tt] = __builtin_amdgcn_mfma_f32_16x16x32_bf16(wf, xf, acc[tt], 0, 0, 0);
        }
    }
    int grow = m0 + arow;
    bool valid = (arow < rows);
    if (valid) {
        uint2* C2 = C + (size_t)grow * 32;
#pragma unroll
        for (int tt = 0; tt < 8; ++tt) {
            uint2 v; v.x = pack2(acc[tt][0], acc[tt][1]); v.y = pack2(acc[tt][2], acc[tt][3]);
            C2[4 * tt + g] = v;
        }
    }
    float ps0 = 0.f, ps1 = 0.f, ps2 = 0.f, ps3 = 0.f;
    float pd0 = 0.f, pd1 = 0.f, pd2 = 0.f, pd3 = 0.f;
#pragma unroll
    for (int tt = 0; tt < 8; ++tt) {
        int h = tt >> 1;
        int fin = 16 * (tt & 1) + 4 * g;
        float4 alv = *(const float4*)(aux + h * 64 + fin);
        float4 arv = *(const float4*)(aux + h * 64 + 32 + fin);
        float s4 = acc[tt][0] * alv.x + acc[tt][1] * alv.y + acc[tt][2] * alv.z + acc[tt][3] * alv.w;
        float d4 = acc[tt][0] * arv.x + acc[tt][1] * arv.y + acc[tt][2] * arv.z + acc[tt][3] * arv.w;
        if (h == 0) { ps0 += s4; pd0 += d4; }
        else if (h == 1) { ps1 += s4; pd1 += d4; }
        else if (h == 2) { ps2 += s4; pd2 += d4; }
        else { ps3 += s4; pd3 += d4; }
    }
#pragma unroll
    for (int mask = 16; mask <= 32; mask <<= 1) {
        ps0 += __shfl_xor(ps0, mask); ps1 += __shfl_xor(ps1, mask);
        ps2 += __shfl_xor(ps2, mask); ps3 += __shfl_xor(ps3, mask);
        pd0 += __shfl_xor(pd0, mask); pd1 += __shfl_xor(pd1, mask);
        pd2 += __shfl_xor(pd2, mask); pd3 += __shfl_xor(pd3, mask);
    }
    if (valid) {
        float psg = (g == 0) ? ps0 : (g == 1) ? ps1 : (g == 2) ? ps2 : ps3;
        float pdg = (g == 0) ? pd0 : (g == 1) ? pd1 : (g == 2) ? pd2 : pd3;
        es[grow * 4 + g] = psg;
        ed[grow * 4 + g] = pdg;
    }
}

// ---------------- P2a: per-bucket scan over partition blocks ----------------
__global__ void k_p2a(const int* __restrict__ hist2d, int* __restrict__ off2d,
                      int* __restrict__ bucktot) {
    __shared__ int sh[512];
    int b = blockIdx.x, t = threadIdx.x;
    int v = (t < PBLK) ? hist2d[b * PBLK + t] : 0;
    sh[t] = v;
    __syncthreads();
    for (int ofs = 1; ofs < 512; ofs <<= 1) {
        int u = (t >= ofs) ? sh[t - ofs] : 0;
        __syncthreads();
        sh[t] += u;
        __syncthreads();
    }
    if (t < PBLK) off2d[b * PBLK + t] = sh[t] - v;
    if (t == 511) bucktot[b] = sh[511];
}

// ---------------- P2b: scan bucket totals -> bucketbase ----------------
__global__ void k_p2b(const int* __restrict__ bucktot, int* __restrict__ bucketbase) {
    __shared__ int sh[512];
    int t = threadIdx.x;
    int v = (t < NBUCK) ? bucktot[t] : 0;
    sh[t] = v;
    __syncthreads();
    for (int ofs = 1; ofs < 512; ofs <<= 1) {
        int u = (t >= ofs) ? sh[t - ofs] : 0;
        __syncthreads();
        sh[t] += u;
        __syncthreads();
    }
    if (t < NBUCK) bucketbase[t] = sh[t] - v;
    if (t == 511) bucketbase[NBUCK] = sh[511];
}

// ---------------- P3: partition edges into bucket-grouped part[] ----------------
__global__ void k_p3(const int* __restrict__ ei, const int* __restrict__ off2d,
                     const int* __restrict__ bucketbase, unsigned* __restrict__ part) {
    __shared__ int h[NBUCK];
    __shared__ int basebuf[NBUCK];
    int blk = blockIdx.x, t = threadIdx.x;
    for (int i = t; i < NBUCK; i += 256) {
        h[i] = 0;
        basebuf[i] = bucketbase[i] + off2d[i * PBLK + blk];
    }
    __syncthreads();
    int base = blk * EPB;
    for (int i = t; i < EPB; i += 256) {
        int e = base + i;
        if (e >= E_TOT) break;
        int col, src;
        if (e < E_RAW) { col = ei[E_RAW + e]; src = ei[e]; }
        else { col = src = e - E_RAW; }
        int b = col >> 7;
        int lr = atomicAdd(&h[b], 1);
        part[basebuf[b] + lr] = (unsigned)src | ((unsigned)(col & 127) << 16);
    }
}

// ---------------- P4: per-bucket col histogram + scan -> off[] and srcs[] ----------------
__global__ void k_p4(const unsigned* __restrict__ part, const int* __restrict__ bucketbase,
                     int* __restrict__ off, unsigned short* __restrict__ srcs) {
    __shared__ int h[128];
    __shared__ int colofs[128];
    int b = blockIdx.x, t = threadIdx.x;
    int s0 = bucketbase[b], s1 = bucketbase[b + 1];
    if (t < 128) h[t] = 0;
    __syncthreads();
    for (int i = s0 + t; i < s1; i += 256) atomicAdd(&h[part[i] >> 16], 1);
    __syncthreads();
    if (t == 0) {
        int acc = 0;
        for (int c = 0; c < 128; ++c) { colofs[c] = acc; acc += h[c]; }
    }
    __syncthreads();
    int colbase = b * 128, ncols = min(128, N_NODES - colbase);
    if (t < ncols) off[colbase + t] = s0 + colofs[t];
    if (b == NBUCK - 1 && t == 0) off[N_NODES] = s1;
    if (t < 128) h[t] = colofs[t];     // reuse as cursors
    __syncthreads();
    for (int i = s0 + t; i < s1; i += 256) {
        unsigned u = part[i];
        int c = u >> 16;
        int slot = atomicAdd(&h[c], 1);
        srcs[s0 + slot] = (unsigned short)(u & 0xffffu);
    }
}

// ---------------- GEMM2 MFMA: h2 = out1b(bf16) @ W2, K=128, N=64 + attn2 epilogue ----------------
__global__ void k_gemm2m(const unsigned* __restrict__ A, const unsigned* __restrict__ B2tg,
                         const float* __restrict__ aux, uint2* __restrict__ C,
                         float* __restrict__ es, float* __restrict__ ed) {
    __shared__ unsigned As[64 * 64];   // 16 KB: 64 rows x 128 bf16, swizzled
    int t = threadIdx.x;
    int m0 = blockIdx.x * 64;
    int rows = min(64, N_NODES - m0);
    const uint4* A4 = (const uint4*)(A + (size_t)m0 * 64);
    for (int i = t; i < rows * 16; i += 256) {
        int row = i >> 4, q = i & 15;
        uint4 v = A4[i];
        int byte = (q * 16) ^ ((row & 7) << 4);
        unsigned* p = &As[row * 64 + (byte >> 2)];
        p[0] = v.x; p[1] = v.y; p[2] = v.z; p[3] = v.w;
    }
    __syncthreads();
    int lane = t & 63, wave = t >> 6;
    int r15 = lane & 15, g = lane >> 4;
    int arow = wave * 16 + r15;
    f32x4 acc[4];
#pragma unroll
    for (int i = 0; i < 4; ++i) acc[i] = (f32x4){0.f, 0.f, 0.f, 0.f};
    const char* Abase = (const char*)As + arow * 256;
    int swz = (arow & 7) << 4;
    const char* Bbase = (const char*)B2tg;
#pragma unroll
    for (int s = 0; s < 4; ++s) {
        bf16x8 xf = *(const bf16x8*)(Abase + ((64 * s + 16 * g) ^ swz));
#pragma unroll
        for (int tt = 0; tt < 4; ++tt) {
            bf16x8 wf = *(const bf16x8*)(Bbase + ((16 * tt + r15) * 256 + 64 * s + 16 * g));
            acc[tt] = __builtin_amdgcn_mfma_f32_16x16x32_bf16(wf, xf, acc[tt], 0, 0, 0);
        }
    }
    int grow = m0 + arow;
    bool valid = (arow < rows);
    if (valid) {
        uint2* C2 = C + (size_t)grow * 16;
#pragma unroll
        for (int tt = 0; tt < 4; ++tt) {
            uint2 v; v.x = pack2(acc[tt][0], acc[tt][1]); v.y = pack2(acc[tt][2], acc[tt][3]);
            C2[4 * tt + g] = v;
        }
    }
    // attn2 epilogue: feature f = 16tt+4g+j; es2 = h2 . aux[0:64], ed2 = h2 . aux[64:128]
    float pl = 0.f, pr = 0.f;
#pragma unroll
    for (int tt = 0; tt < 4; ++tt) {
        int f0 = 16 * tt + 4 * g;
        float4 alv = *(const float4*)(aux + f0);
        float4 arv = *(const float4*)(aux + 64 + f0);
        pl += acc[tt][0] * alv.x + acc[tt][1] * alv.y + acc[tt][2] * alv.z + acc[tt][3] * alv.w;
        pr += acc[tt][0] * arv.x + acc[tt][1] * arv.y + acc[tt][2] * arv.z + acc[tt][3] * arv.w;
    }
#pragma unroll
    for (int mask = 16; mask <= 32; mask <<= 1) {
        pl += __shfl_xor(pl, mask);
        pr += __shfl_xor(pr, mask);
    }
    if (valid && g == 0) { es[grow] = pl; ed[grow] = pr; }
}

// ---------------- head GEMM (fp32 VALU, K=64, N=64) ----------------
__global__ void k_head(const float* __restrict__ A, const float* __restrict__ B,
                       const float* __restrict__ aux, float* __restrict__ Cv) {
    constexpr int K = 64, MT = 32;
    __shared__ float As[MT * K];
    int m0 = blockIdx.x * MT;
    int t = threadIdx.x, g = t >> 4, l = t & 15;
    int rows = min(MT, N_NODES - m0);
    const float4* A4 = (const float4*)(A + (size_t)m0 * K);
    float4* S4 = (float4*)As;
    for (int i = t; i < rows * (K / 4); i += 64) S4[i] = A4[i];
    __syncthreads();
    float acc[8][4];
#pragma unroll
    for (int r = 0; r < 8; ++r)
#pragma unroll
        for (int c = 0; c < 4; ++c) acc[r][c] = 0.f;
    const float4* B4 = (const float4*)B;
    for (int kk = 0; kk < K / 4; ++kk) {
        float4 b0 = B4[(4 * kk + 0) * 16 + l];
        float4 b1 = B4[(4 * kk + 1) * 16 + l];
        float4 b2 = B4[(4 * kk + 2) * 16 + l];
        float4 b3 = B4[(4 * kk + 3) * 16 + l];
#pragma unroll
        for (int r = 0; r < 8; ++r) {
            float4 a = ((const float4*)(As + (g * 8 + r) * K))[kk];
            acc[r][0] = fmaf(a.x, b0.x, fmaf(a.y, b1.x, fmaf(a.z, b2.x, fmaf(a.w, b3.x, acc[r][0]))));
            acc[r][1] = fmaf(a.x, b0.y, fmaf(a.y, b1.y, fmaf(a.z, b2.y, fmaf(a.w, b3.y, acc[r][1]))));
            acc[r][2] = fmaf(a.x, b0.z, fmaf(a.y, b1.z, fmaf(a.z, b2.z, fmaf(a.w, b3.z, acc[r][2]))));
            acc[r][3] = fmaf(a.x, b0.w, fmaf(a.y, b1.w, fmaf(a.z, b2.w, fmaf(a.w, b3.w, acc[r][3]))));
        }
    }
    float4* C = (float4*)Cv;
    float4 bv = ((const float4*)aux)[l];
#pragma unroll
    for (int r = 0; r < 8; ++r) {
        int row = m0 + g * 8 + r;
        if (row < N_NODES) {
            float4 v;
            v.x = acc[r][0] + bv.x; v.y = acc[r][1] + bv.y;
            v.z = acc[r][2] + bv.z; v.w = acc[r][3] + bv.w;
            C[(size_t)row * 16 + l] = v;
        }
    }
}

// ---------------- layer-1 fused softmax+aggregate: one wave per node ----------------
// Writes out1 as bf16 (pack2) -> halves traffic & feeds gemm2m directly.
// Tail-trimmed: wave-uniform guard j2<cnt skips dead gathers/shuffles in the last chunk.
__global__ void k_agg1(const unsigned* __restrict__ h1b, const float* __restrict__ es,
                       const float* __restrict__ ed, const int* __restrict__ off,
                       const unsigned short* __restrict__ srcs, unsigned* __restrict__ out1) {
    int n = blockIdx.x * (blockDim.x >> 6) + (threadIdx.x >> 6);
    int lane = threadIdx.x & 63;
    if (n >= N_NODES) return;
    int myh = lane & 3;
    float edh = ed[n * 4 + myh];
    int hc = lane >> 4;
    int s = off[n], e = off[n + 1];
    int jj = lane >> 2;
    float ax = 0.f, ay = 0.f, psum = 0.f;
    for (int base = s; base < e; base += 16) {
        int cnt = e - base;            // wave-uniform
        int srcj = 0;
        float w = 0.f;
        if (jj < cnt) {
            srcj = srcs[base + jj];
            w = __expf(lrelu(es[srcj * 4 + myh] + edh));
        }
        psum += w;
        unsigned pv[16];
        float wv[16];
#pragma unroll
        for (int j2 = 0; j2 < 16; ++j2) {
            if (j2 < cnt) {
                int src = __shfl(srcj, j2 * 4);
                wv[j2] = __shfl(w, j2 * 4 + hc);
                pv[j2] = h1b[(size_t)src * 64 + lane];
            } else {
                wv[j2] = 0.f; pv[j2] = 0u;
            }
        }
#pragma unroll
        for (int j2 = 0; j2 < 16; ++j2) {
            ax = fmaf(bflo(pv[j2]), wv[j2], ax);
            ay = fmaf(bfhi(pv[j2]), wv[j2], ay);
        }
    }
#pragma unroll
    for (int mask = 4; mask <= 32; mask <<= 1) psum += __shfl_xor(psum, mask);
    float inv = 1.f / __shfl(psum, hc);
    out1[(size_t)n * 64 + lane] = pack2(fmaxf(ax * inv, 0.f), fmaxf(ay * inv, 0.f));
}

// ---------------- layer-2 fused softmax+aggregate: half-wave per node ----------------
__global__ void k_agg2(const unsigned* __restrict__ h2b, const float* __restrict__ es,
                       const float* __restrict__ ed, const int* __restrict__ off,
                       const unsigned short* __restrict__ srcs, float* __restrict__ outv) {
    int n = blockIdx.x * (blockDim.x >> 5) + (threadIdx.x >> 5);
    int l = threadIdx.x & 31;
    int hb = threadIdx.x & 32;
    if (n >= N_NODES) return;
    float edv = ed[n];
    int s = off[n], e = off[n + 1];
    const uint2* gp = (const uint2*)h2b;
    int l16 = l & 15;
    int sb0 = (l >> 4) * 2;
    float a0 = 0.f, a1 = 0.f, a2 = 0.f, a3 = 0.f, psum = 0.f;
    for (int base = s; base < e; base += 32) {
        int cnt = e - base;
        int srcj = 0;
        float w = 0.f;
        if (l < cnt) {
            srcj = srcs[base + l];
            w = __expf(lrelu(es[srcj] + edv));
        }
        psum += w;
#pragma unroll
        for (int sub = 0; sub < 2; ++sub) {
            uint2 pv[8];
            float wv[8];
#pragma unroll
            for (int j = 0; j < 8; ++j) {
                int lsrc = hb + (sb0 + sub) * 8 + j;
                int src = __shfl(srcj, lsrc);
                wv[j] = __shfl(w, lsrc);
                pv[j] = gp[(size_t)src * 16 + l16];
            }
#pragma unroll
            for (int j = 0; j < 8; ++j) {
                a0 = fmaf(bflo(pv[j].x), wv[j], a0);
                a1 = fmaf(bfhi(pv[j].x), wv[j], a1);
                a2 = fmaf(bflo(pv[j].y), wv[j], a2);
                a3 = fmaf(bfhi(pv[j].y), wv[j], a3);
            }
        }
    }
#pragma unroll
    for (int mask = 1; mask <= 16; mask <<= 1) psum += __shfl_xor(psum, mask);
    float inv = 1.f / psum;
    a0 += __shfl_xor(a0, 16); a1 += __shfl_xor(a1, 16);
    a2 += __shfl_xor(a2, 16); a3 += __shfl_xor(a3, 16);
    if (l < 16) {
        float4 o;
        o.x = a0 * inv; o.y = a1 * inv; o.z = a2 * inv; o.w = a3 * inv;
        ((float4*)outv)[(size_t)n * 16 + l16] = o;
    }
}

extern "C" void kernel_launch(void* const* d_in, const int* in_sizes, int n_in,
                              void* d_out, int out_size, void* d_ws, size_t ws_size,
                              hipStream_t stream) {
    const float* x     = (const float*)d_in[0];
    const int*   ei    = (const int*)d_in[1];
    const float* W1    = (const float*)d_in[2];
    const float* attn1 = (const float*)d_in[3];
    const float* W2    = (const float*)d_in[4];
    const float* attn2 = (const float*)d_in[5];
    const float* headW = (const float*)d_in[6];
    const float* headb = (const float*)d_in[7];
    float* out = (float*)d_out;

    char* ws = (char*)d_ws;
    size_t o = 0;
    auto alloc = [&](size_t bytes) -> void* {
        o = (o + 255) & ~(size_t)255;
        void* p = ws + o;
        o += bytes;
        return p;
    };
    unsigned*       h1b    = (unsigned*)alloc((size_t)N_NODES * 128 * 2);
    unsigned*       out1b  = (unsigned*)alloc((size_t)N_NODES * 128 * 2);  // bf16 now
    unsigned*       h2b    = (unsigned*)alloc((size_t)N_NODES * 64 * 2);
    float*          h2agg  = (float*)alloc((size_t)N_NODES * 64 * 4);
    float*          e1s    = (float*)alloc((size_t)N_NODES * 4 * 4);
    float*          e1d    = (float*)alloc((size_t)N_NODES * 4 * 4);
    float*          e2s    = (float*)alloc((size_t)N_NODES * 4);
    float*          e2d    = (float*)alloc((size_t)N_NODES * 4);
    int*            off    = (int*)alloc((size_t)(N_NODES + 1) * 4);
    unsigned short* srcs   = (unsigned short*)alloc((size_t)E_TOT * 2);
    unsigned*       Btg    = (unsigned*)alloc((size_t)128 * 64 * 4);   // W1^T bf16
    unsigned*       B2tg   = (unsigned*)alloc((size_t)64 * 64 * 4);    // W2^T bf16
    int*            hist2d = (int*)alloc((size_t)NBUCK * PBLK * 4);    // [bucket][blk]
    int*            off2d  = (int*)alloc((size_t)NBUCK * PBLK * 4);
    int*            bucktot = (int*)alloc((size_t)NBUCK * 4);
    int*            bucketbase = (int*)alloc((size_t)(NBUCK + 1) * 4);
    unsigned*       part   = (unsigned*)alloc((size_t)E_TOT * 4);      // src | collow<<16

    // prep W1^T + W2^T bf16 (48KB total, stays hot in L2)
    k_prep<<<192, 64, 0, stream>>>(W1, W2, Btg, B2tg);

    // fused: gemm1 MFMA (+attn1 epilogue) || P1 bucket histogram (LDS atomics only)
    k_gemm1_p1<<<G1_BLOCKS + PBLK, 256, 0, stream>>>(
        x, Btg, attn1, (uint2*)h1b, e1s, e1d, ei, hist2d);

    // CSR build: scans + partition + per-bucket finalize (no global atomics anywhere)
    k_p2a<<<NBUCK, 512, 0, stream>>>(hist2d, off2d, bucktot);
    k_p2b<<<1, 512, 0, stream>>>(bucktot, bucketbase);
    k_p3<<<PBLK, 256, 0, stream>>>(ei, off2d, bucketbase, part);
    k_p4<<<NBUCK, 256, 0, stream>>>(part, bucketbase, off, srcs);

    // layer 1 aggregate (writes bf16 out1b)
    k_agg1<<<N_NODES / 4, 256, 0, stream>>>(h1b, e1s, e1d, off, srcs, out1b);

    // layer 2: MFMA gemm + aggregate
    k_gemm2m<<<(N_NODES + 63) / 64, 256, 0, stream>>>(out1b, B2tg, attn2, (uint2*)h2b, e2s, e2d);
    k_agg2<<<N_NODES / 8, 256, 0, stream>>>(h2b, e2s, e2d, off, srcs, h2agg);

    // head
    k_head<<<(N_NODES + 31) / 32, 64, 0, stream>>>(h2agg, headW, headb, out);
}